// Round 2
// baseline (529.196 us; speedup 1.0000x reference)
//
#include <hip/hip_runtime.h>

// out = dequant( int8_gemm( quant(x, in_scale), quant(w, absmax/127) ) + b_q )
// M = 8192, K = 1600, N = 6400.
// R2: wave tile 64x64 -> 64x128 (block 128x256). GEMM was ds_read_b128
// issue-bound (1142 cyc/iter measured == 8 waves*... see journal); reads/MFMA
// drops 0.5 -> 0.375.

#define M_DIM 8192
#define K_DIM 1600
#define N_DIM 6400
#define QMAXF 127.0f

typedef __attribute__((ext_vector_type(4))) int int4v;

// ---------------- ws layout ----------------
// [0, 4)            : uint bits of max|w|  (atomicMax target; memset to 0 each call)
// [256, 256+M*K)    : x_q  int8, row-major [M][K]
// [.. , ..  +N*K)   : wT_q int8, row-major [N][K]  (transposed weight)

__device__ __forceinline__ void load_lds16(const void* gptr, void* lptr) {
    // global -> LDS direct, 16B per lane; LDS dest = wave-uniform base + lane*16
    __builtin_amdgcn_global_load_lds((__attribute__((address_space(1))) void*)gptr,
                                     (__attribute__((address_space(3))) void*)lptr,
                                     16, 0, 0);
}

// ---------------- absmax(weight) reduction ----------------
__global__ void wmax_kernel(const float* __restrict__ w,
                            unsigned int* __restrict__ wmax_bits, int n4) {
    const float4* w4 = (const float4*)w;
    int i = blockIdx.x * blockDim.x + threadIdx.x;
    int stride = gridDim.x * blockDim.x;
    float m = 0.0f;
    for (; i < n4; i += stride) {
        float4 v = w4[i];
        m = fmaxf(m, fmaxf(fmaxf(fabsf(v.x), fabsf(v.y)),
                           fmaxf(fabsf(v.z), fabsf(v.w))));
    }
#pragma unroll
    for (int off = 32; off > 0; off >>= 1)
        m = fmaxf(m, __shfl_down(m, off, 64));
    if ((threadIdx.x & 63) == 0)
        atomicMax(wmax_bits, __float_as_uint(m));  // m >= 0 -> uint order == float order
}

// ---------------- quantize x -> int8 [M][K] ----------------
__global__ void quantx_kernel(const float* __restrict__ x, signed char* __restrict__ xq,
                              const float* __restrict__ in_scale_p, int n4) {
    int i = blockIdx.x * blockDim.x + threadIdx.x;
    if (i >= n4) return;
    float s = *in_scale_p;
    float4 v = ((const float4*)x)[i];
    float a = fminf(fmaxf(rintf(v.x / s), -128.0f), 127.0f);
    float b = fminf(fmaxf(rintf(v.y / s), -128.0f), 127.0f);
    float c = fminf(fmaxf(rintf(v.z / s), -128.0f), 127.0f);
    float d = fminf(fmaxf(rintf(v.w / s), -128.0f), 127.0f);
    char4 packed = make_char4((signed char)a, (signed char)b,
                              (signed char)c, (signed char)d);
    ((char4*)xq)[i] = packed;
}

// ---------------- quantize + transpose w -> int8 [N][K] ----------------
__global__ void quantw_kernel(const float* __restrict__ w, signed char* __restrict__ wT,
                              const unsigned int* __restrict__ wmax_bits) {
    __shared__ signed char tile[32][33];
    float wscale = __uint_as_float(*wmax_bits) / QMAXF;
    int n0 = blockIdx.x * 32;
    int k0 = blockIdx.y * 32;
    int tx = threadIdx.x;  // 0..31
    int ty = threadIdx.y;  // 0..7
#pragma unroll
    for (int p = 0; p < 4; ++p) {
        int kk = ty + p * 8;
        float v = w[(size_t)(k0 + kk) * N_DIM + n0 + tx];  // coalesced along n
        float q = fminf(fmaxf(rintf(v / wscale), -128.0f), 127.0f);
        tile[kk][tx] = (signed char)q;
    }
    __syncthreads();
#pragma unroll
    for (int p = 0; p < 4; ++p) {
        int nn = ty + p * 8;
        wT[(size_t)(n0 + nn) * K_DIM + k0 + tx] = tile[tx][nn];  // coalesced along k
    }
}

// ---------------- int8 GEMM, 128x256 block, BK=64, fused epilogue ----------------
// 4 waves in 2x2; each wave owns 64x128 = 4x8 tiles of mfma_i32_16x16x64_i8.
// reads/MFMA = (4A+8B)/32 = 0.375 (was 0.5) -> relieves ds_read_b128 issue bound.
__global__ __launch_bounds__(256, 2) void gemm_i8_kernel(
        const signed char* __restrict__ xq, const signed char* __restrict__ wTq,
        const float* __restrict__ bias, const unsigned int* __restrict__ wmax_bits,
        const float* __restrict__ in_scale_p, const float* __restrict__ out_scale_p,
        float* __restrict__ out) {
    __shared__ signed char A_lds[128 * 64];  //  8 KB  [m][k]
    __shared__ signed char B_lds[256 * 64];  // 16 KB  [n][k]

    const int tid   = threadIdx.x;
    const int wave  = tid >> 6;
    const int lane  = tid & 63;
    const int quad  = lane >> 4;
    const int l15   = lane & 15;
    const int waveM = wave >> 1;  // 0..1  (64-row slab of M)
    const int waveN = wave & 1;   // 0..1  (128-row slab of N)

    const int blockN0 = blockIdx.x * 256;
    const int blockM0 = blockIdx.y * 128;

    const signed char* Ag = xq  + (size_t)blockM0 * K_DIM;
    const signed char* Bg = wTq + (size_t)blockN0 * K_DIM;

    // staging: per issue, this wave covers 16 rows x 64B = 1 KB
    const int srow = wave * 16 + (lane >> 2);   // row within 64-row chunk
    const int scol = (lane & 3) * 16;           // byte offset within 64B row

    int4v acc[4][8];
    const int4v zero4 = {0, 0, 0, 0};
#pragma unroll
    for (int i = 0; i < 4; ++i)
#pragma unroll
        for (int j = 0; j < 8; ++j) acc[i][j] = zero4;

    for (int k0 = 0; k0 < K_DIM; k0 += 64) {
#pragma unroll
        for (int t = 0; t < 2; ++t) {   // A: 128 rows = 2 issues
            const int r = t * 64 + srow;
            load_lds16(Ag + (size_t)r * K_DIM + k0 + scol,
                       &A_lds[(t * 64 + wave * 16) * 64]);
        }
#pragma unroll
        for (int t = 0; t < 4; ++t) {   // B: 256 rows = 4 issues
            const int r = t * 64 + srow;
            load_lds16(Bg + (size_t)r * K_DIM + k0 + scol,
                       &B_lds[(t * 64 + wave * 16) * 64]);
        }
        __syncthreads();

        int4v a[4], b[8];
#pragma unroll
        for (int mt = 0; mt < 4; ++mt)
            a[mt] = *(const int4v*)&A_lds[(waveM * 64 + mt * 16 + l15) * 64 + quad * 16];
#pragma unroll
        for (int nt = 0; nt < 8; ++nt)
            b[nt] = *(const int4v*)&B_lds[(waveN * 128 + nt * 16 + l15) * 64 + quad * 16];

#pragma unroll
        for (int mt = 0; mt < 4; ++mt)
#pragma unroll
            for (int nt = 0; nt < 8; ++nt)
                acc[mt][nt] = __builtin_amdgcn_mfma_i32_16x16x64_i8(a[mt], b[nt],
                                                                    acc[mt][nt], 0, 0, 0);
        __syncthreads();
    }

    // epilogue: + b_q, rescale, rint, clip, dequant
    const float s_in  = *in_scale_p;
    const float s_out = *out_scale_p;
    const float wscale = __uint_as_float(*wmax_bits) / QMAXF;
    const float bias_scale = s_in * wscale;
    const float ratio = bias_scale / s_out;

#pragma unroll
    for (int nt = 0; nt < 8; ++nt) {
        const int col = blockN0 + waveN * 128 + nt * 16 + l15;
        const int bq = (int)rintf(bias[col] / bias_scale);
#pragma unroll
        for (int mt = 0; mt < 4; ++mt) {
#pragma unroll
            for (int r = 0; r < 4; ++r) {
                const int row = blockM0 + waveM * 64 + mt * 16 + quad * 4 + r;
                const int av = acc[mt][nt][r] + bq;
                float f = rintf((float)av * ratio);
                f = fminf(fmaxf(f, -128.0f), 127.0f);
                out[(size_t)row * N_DIM + col] = f * s_out;
            }
        }
    }
}

extern "C" void kernel_launch(void* const* d_in, const int* in_sizes, int n_in,
                              void* d_out, int out_size, void* d_ws, size_t ws_size,
                              hipStream_t stream) {
    const float* x         = (const float*)d_in[0];
    const float* w         = (const float*)d_in[1];
    const float* bias      = (const float*)d_in[2];
    const float* in_scale  = (const float*)d_in[3];
    const float* out_scale = (const float*)d_in[4];
    float* out = (float*)d_out;

    unsigned char* ws = (unsigned char*)d_ws;
    unsigned int* wmax_bits = (unsigned int*)ws;
    signed char* xq  = (signed char*)(ws + 256);
    signed char* wTq = (signed char*)(ws + 256 + (size_t)M_DIM * K_DIM);

    hipMemsetAsync(d_ws, 0, 256, stream);

    wmax_kernel<<<2560, 256, 0, stream>>>(w, wmax_bits, (K_DIM * N_DIM) / 4);

    quantx_kernel<<<(M_DIM * K_DIM / 4 + 255) / 256, 256, 0, stream>>>(
        x, xq, in_scale, M_DIM * K_DIM / 4);

    dim3 wgrid(N_DIM / 32, K_DIM / 32);
    quantw_kernel<<<wgrid, dim3(32, 8), 0, stream>>>(w, wTq, wmax_bits);

    dim3 ggrid(N_DIM / 256, M_DIM / 128);  // (25, 64)
    gemm_i8_kernel<<<ggrid, 256, 0, stream>>>(xq, wTq, bias, wmax_bits,
                                              in_scale, out_scale, out);
}

// Round 3
// 418.113 us; speedup vs baseline: 1.2657x; 1.2657x over previous
//
#include <hip/hip_runtime.h>

// out = dequant( int8_gemm( quant(x, in_scale), quant(w, absmax/127) ) + b_q )
// M = 8192, K = 1600, N = 6400.
// R3: GEMM reverted to R1 shape (128x128, 64x64 wave tile — R2's bigger tile
// halved occupancy and regressed; kernel is barrier/latency-bound).
// Pre-pass fixes: wmax 10240 same-address atomics -> 320; quantw byte stores
// -> 16B/thread dwordx4 stores.

#define M_DIM 8192
#define K_DIM 1600
#define N_DIM 6400
#define QMAXF 127.0f

typedef __attribute__((ext_vector_type(4))) int int4v;

// ---------------- ws layout ----------------
// [0, 4)            : uint bits of max|w|  (atomicMax target; memset to 0 each call)
// [256, 256+M*K)    : x_q  int8, row-major [M][K]
// [.. , ..  +N*K)   : wT_q int8, row-major [N][K]  (transposed weight)

__device__ __forceinline__ void load_lds16(const void* gptr, void* lptr) {
    __builtin_amdgcn_global_load_lds((__attribute__((address_space(1))) void*)gptr,
                                     (__attribute__((address_space(3))) void*)lptr,
                                     16, 0, 0);
}

// ---------------- absmax(weight): wave reduce -> LDS -> 1 atomic/block ----------------
__global__ void wmax_kernel(const float* __restrict__ w,
                            unsigned int* __restrict__ wmax_bits, int n4) {
    __shared__ float smax[4];
    const float4* w4 = (const float4*)w;
    int i = blockIdx.x * blockDim.x + threadIdx.x;
    int stride = gridDim.x * blockDim.x;
    float m = 0.0f;
    for (; i < n4; i += stride) {
        float4 v = w4[i];
        m = fmaxf(m, fmaxf(fmaxf(fabsf(v.x), fabsf(v.y)),
                           fmaxf(fabsf(v.z), fabsf(v.w))));
    }
#pragma unroll
    for (int off = 32; off > 0; off >>= 1)
        m = fmaxf(m, __shfl_down(m, off, 64));
    const int wave = threadIdx.x >> 6;
    if ((threadIdx.x & 63) == 0) smax[wave] = m;
    __syncthreads();
    if (threadIdx.x == 0) {
        float mm = fmaxf(fmaxf(smax[0], smax[1]), fmaxf(smax[2], smax[3]));
        atomicMax(wmax_bits, __float_as_uint(mm));  // mm >= 0: uint order == float order
    }
}

// ---------------- quantize x -> int8 [M][K] ----------------
__global__ void quantx_kernel(const float* __restrict__ x, signed char* __restrict__ xq,
                              const float* __restrict__ in_scale_p, int n4) {
    int i = blockIdx.x * blockDim.x + threadIdx.x;
    if (i >= n4) return;
    float s = *in_scale_p;
    float4 v = ((const float4*)x)[i];
    float a = fminf(fmaxf(rintf(v.x / s), -128.0f), 127.0f);
    float b = fminf(fmaxf(rintf(v.y / s), -128.0f), 127.0f);
    float c = fminf(fmaxf(rintf(v.z / s), -128.0f), 127.0f);
    float d = fminf(fmaxf(rintf(v.w / s), -128.0f), 127.0f);
    char4 packed = make_char4((signed char)a, (signed char)b,
                              (signed char)c, (signed char)d);
    ((char4*)xq)[i] = packed;
}

// ---------------- quantize + transpose w -> int8 [N][K], 64x64 tile ----------------
// Reads coalesced along n (256B/wave); stores 16B/thread along k (64B per 4 lanes).
__global__ void quantw_kernel(const float* __restrict__ w, signed char* __restrict__ wT,
                              const unsigned int* __restrict__ wmax_bits) {
    __shared__ signed char tile[64 * 80];  // [n][k], stride 80 keeps 16B alignment
    const float wscale = __uint_as_float(*wmax_bits) / QMAXF;
    const int n0 = blockIdx.x * 64;
    const int k0 = blockIdx.y * 64;
    const int tid = threadIdx.x;
    const int nn = tid & 63;
    const int kb = tid >> 6;  // 0..3
#pragma unroll
    for (int p = 0; p < 16; ++p) {
        const int kk = p * 4 + kb;
        float v = w[(size_t)(k0 + kk) * N_DIM + n0 + nn];  // coalesced along n
        float q = fminf(fmaxf(rintf(v / wscale), -128.0f), 127.0f);
        tile[nn * 80 + kk] = (signed char)q;               // transposed in LDS
    }
    __syncthreads();
    const int n_loc = tid >> 2;
    const int kq = tid & 3;
    int4v val = *(const int4v*)&tile[n_loc * 80 + kq * 16];
    *(int4v*)&wT[(size_t)(n0 + n_loc) * K_DIM + k0 + kq * 16] = val;
}

// ---------------- int8 GEMM, 128x128 tile, BK=64, fused epilogue (R1 shape) ----------
__global__ __launch_bounds__(256, 2) void gemm_i8_kernel(
        const signed char* __restrict__ xq, const signed char* __restrict__ wTq,
        const float* __restrict__ bias, const unsigned int* __restrict__ wmax_bits,
        const float* __restrict__ in_scale_p, const float* __restrict__ out_scale_p,
        float* __restrict__ out) {
    __shared__ signed char A_lds[128 * 64];  // 8 KB  [m][k]
    __shared__ signed char B_lds[128 * 64];  // 8 KB  [n][k]

    const int tid   = threadIdx.x;
    const int wave  = tid >> 6;
    const int lane  = tid & 63;
    const int quad  = lane >> 4;
    const int l15   = lane & 15;
    const int waveM = wave >> 1;
    const int waveN = wave & 1;

    const int blockN0 = blockIdx.x * 128;
    const int blockM0 = blockIdx.y * 128;

    const signed char* Ag = xq  + (size_t)blockM0 * K_DIM;
    const signed char* Bg = wTq + (size_t)blockN0 * K_DIM;

    const int srow = wave * 16 + (lane >> 2);
    const int scol = (lane & 3) * 16;

    int4v acc[4][4];
    const int4v zero4 = {0, 0, 0, 0};
#pragma unroll
    for (int i = 0; i < 4; ++i)
#pragma unroll
        for (int j = 0; j < 4; ++j) acc[i][j] = zero4;

    for (int k0 = 0; k0 < K_DIM; k0 += 64) {
#pragma unroll
        for (int t = 0; t < 2; ++t) {
            const int r = t * 64 + srow;
            load_lds16(Ag + (size_t)r * K_DIM + k0 + scol,
                       &A_lds[(t * 64 + wave * 16) * 64]);
            load_lds16(Bg + (size_t)r * K_DIM + k0 + scol,
                       &B_lds[(t * 64 + wave * 16) * 64]);
        }
        __syncthreads();

        int4v a[4], b[4];
#pragma unroll
        for (int mt = 0; mt < 4; ++mt)
            a[mt] = *(const int4v*)&A_lds[(waveM * 64 + mt * 16 + l15) * 64 + quad * 16];
#pragma unroll
        for (int nt = 0; nt < 4; ++nt)
            b[nt] = *(const int4v*)&B_lds[(waveN * 64 + nt * 16 + l15) * 64 + quad * 16];

#pragma unroll
        for (int mt = 0; mt < 4; ++mt)
#pragma unroll
            for (int nt = 0; nt < 4; ++nt)
                acc[mt][nt] = __builtin_amdgcn_mfma_i32_16x16x64_i8(a[mt], b[nt],
                                                                    acc[mt][nt], 0, 0, 0);
        __syncthreads();
    }

    const float s_in  = *in_scale_p;
    const float s_out = *out_scale_p;
    const float wscale = __uint_as_float(*wmax_bits) / QMAXF;
    const float bias_scale = s_in * wscale;
    const float ratio = bias_scale / s_out;

#pragma unroll
    for (int nt = 0; nt < 4; ++nt) {
        const int col = blockN0 + waveN * 64 + nt * 16 + l15;
        const int bq = (int)rintf(bias[col] / bias_scale);
#pragma unroll
        for (int mt = 0; mt < 4; ++mt) {
#pragma unroll
            for (int r = 0; r < 4; ++r) {
                const int row = blockM0 + waveM * 64 + mt * 16 + quad * 4 + r;
                const int av = acc[mt][nt][r] + bq;
                float f = rintf((float)av * ratio);
                f = fminf(fmaxf(f, -128.0f), 127.0f);
                out[(size_t)row * N_DIM + col] = f * s_out;
            }
        }
    }
}

extern "C" void kernel_launch(void* const* d_in, const int* in_sizes, int n_in,
                              void* d_out, int out_size, void* d_ws, size_t ws_size,
                              hipStream_t stream) {
    const float* x         = (const float*)d_in[0];
    const float* w         = (const float*)d_in[1];
    const float* bias      = (const float*)d_in[2];
    const float* in_scale  = (const float*)d_in[3];
    const float* out_scale = (const float*)d_in[4];
    float* out = (float*)d_out;

    unsigned char* ws = (unsigned char*)d_ws;
    unsigned int* wmax_bits = (unsigned int*)ws;
    signed char* xq  = (signed char*)(ws + 256);
    signed char* wTq = (signed char*)(ws + 256 + (size_t)M_DIM * K_DIM);

    hipMemsetAsync(d_ws, 0, 256, stream);

    wmax_kernel<<<320, 256, 0, stream>>>(w, wmax_bits, (K_DIM * N_DIM) / 4);

    quantx_kernel<<<(M_DIM * K_DIM / 4 + 255) / 256, 256, 0, stream>>>(
        x, xq, in_scale, M_DIM * K_DIM / 4);

    dim3 wgrid(N_DIM / 64, K_DIM / 64);  // (100, 25)
    quantw_kernel<<<wgrid, 256, 0, stream>>>(w, wTq, wmax_bits);

    dim3 ggrid(N_DIM / 128, M_DIM / 128);  // (50, 64)
    gemm_i8_kernel<<<ggrid, 256, 0, stream>>>(xq, wTq, bias, wmax_bits,
                                              in_scale, out_scale, out);
}

// Round 4
// 417.903 us; speedup vs baseline: 1.2663x; 1.0005x over previous
//
#include <hip/hip_runtime.h>

// out = dequant( int8_gemm( quant(x, in_scale), quant(w, absmax/127) ) + b_q )
// M = 8192, K = 1600, N = 6400.
// R4: double-buffered LDS in GEMM. R3 accounting: per block-iter 1121 cyc,
// only ~450 busy (LDS 34%, MFMA 24%) -> ~600 cyc exposed global_load_lds
// latency (single-buffer issues loads right before the vmcnt(0) barrier).
// Prefetch next K-tile into alt buffer after the barrier, compute current.

#define M_DIM 8192
#define K_DIM 1600
#define N_DIM 6400
#define QMAXF 127.0f

typedef __attribute__((ext_vector_type(4))) int int4v;

// ---------------- ws layout ----------------
// [0, 4)            : uint bits of max|w|  (atomicMax target; memset to 0 each call)
// [256, 256+M*K)    : x_q  int8, row-major [M][K]
// [.. , ..  +N*K)   : wT_q int8, row-major [N][K]  (transposed weight)

__device__ __forceinline__ void load_lds16(const void* gptr, void* lptr) {
    __builtin_amdgcn_global_load_lds((__attribute__((address_space(1))) void*)gptr,
                                     (__attribute__((address_space(3))) void*)lptr,
                                     16, 0, 0);
}

// ---------------- absmax(weight): wave reduce -> LDS -> 1 atomic/block ----------------
__global__ void wmax_kernel(const float* __restrict__ w,
                            unsigned int* __restrict__ wmax_bits, int n4) {
    __shared__ float smax[4];
    const float4* w4 = (const float4*)w;
    int i = blockIdx.x * blockDim.x + threadIdx.x;
    int stride = gridDim.x * blockDim.x;
    float m = 0.0f;
    for (; i < n4; i += stride) {
        float4 v = w4[i];
        m = fmaxf(m, fmaxf(fmaxf(fabsf(v.x), fabsf(v.y)),
                           fmaxf(fabsf(v.z), fabsf(v.w))));
    }
#pragma unroll
    for (int off = 32; off > 0; off >>= 1)
        m = fmaxf(m, __shfl_down(m, off, 64));
    const int wave = threadIdx.x >> 6;
    if ((threadIdx.x & 63) == 0) smax[wave] = m;
    __syncthreads();
    if (threadIdx.x == 0) {
        float mm = fmaxf(fmaxf(smax[0], smax[1]), fmaxf(smax[2], smax[3]));
        atomicMax(wmax_bits, __float_as_uint(mm));  // mm >= 0: uint order == float order
    }
}

// ---------------- quantize x -> int8 [M][K] ----------------
__global__ void quantx_kernel(const float* __restrict__ x, signed char* __restrict__ xq,
                              const float* __restrict__ in_scale_p, int n4) {
    int i = blockIdx.x * blockDim.x + threadIdx.x;
    if (i >= n4) return;
    float s = *in_scale_p;
    float4 v = ((const float4*)x)[i];
    float a = fminf(fmaxf(rintf(v.x / s), -128.0f), 127.0f);
    float b = fminf(fmaxf(rintf(v.y / s), -128.0f), 127.0f);
    float c = fminf(fmaxf(rintf(v.z / s), -128.0f), 127.0f);
    float d = fminf(fmaxf(rintf(v.w / s), -128.0f), 127.0f);
    char4 packed = make_char4((signed char)a, (signed char)b,
                              (signed char)c, (signed char)d);
    ((char4*)xq)[i] = packed;
}

// ---------------- quantize + transpose w -> int8 [N][K], 64x64 tile ----------------
__global__ void quantw_kernel(const float* __restrict__ w, signed char* __restrict__ wT,
                              const unsigned int* __restrict__ wmax_bits) {
    __shared__ signed char tile[64 * 80];  // [n][k], stride 80 keeps 16B alignment
    const float wscale = __uint_as_float(*wmax_bits) / QMAXF;
    const int n0 = blockIdx.x * 64;
    const int k0 = blockIdx.y * 64;
    const int tid = threadIdx.x;
    const int nn = tid & 63;
    const int kb = tid >> 6;  // 0..3
#pragma unroll
    for (int p = 0; p < 16; ++p) {
        const int kk = p * 4 + kb;
        float v = w[(size_t)(k0 + kk) * N_DIM + n0 + nn];  // coalesced along n
        float q = fminf(fmaxf(rintf(v / wscale), -128.0f), 127.0f);
        tile[nn * 80 + kk] = (signed char)q;               // transposed in LDS
    }
    __syncthreads();
    const int n_loc = tid >> 2;
    const int kq = tid & 3;
    int4v val = *(const int4v*)&tile[n_loc * 80 + kq * 16];
    *(int4v*)&wT[(size_t)(n0 + n_loc) * K_DIM + k0 + kq * 16] = val;
}

// ------- int8 GEMM, 128x128 tile, BK=64, double-buffered LDS, fused epilogue -------
__global__ __launch_bounds__(256, 2) void gemm_i8_kernel(
        const signed char* __restrict__ xq, const signed char* __restrict__ wTq,
        const float* __restrict__ bias, const unsigned int* __restrict__ wmax_bits,
        const float* __restrict__ in_scale_p, const float* __restrict__ out_scale_p,
        float* __restrict__ out) {
    __shared__ signed char A_lds[2][128 * 64];  // 2 x 8 KB  [m][k]
    __shared__ signed char B_lds[2][128 * 64];  // 2 x 8 KB  [n][k]

    const int tid   = threadIdx.x;
    const int wave  = tid >> 6;
    const int lane  = tid & 63;
    const int quad  = lane >> 4;
    const int l15   = lane & 15;
    const int waveM = wave >> 1;
    const int waveN = wave & 1;

    const int blockN0 = blockIdx.x * 128;
    const int blockM0 = blockIdx.y * 128;

    const signed char* Ag = xq  + (size_t)blockM0 * K_DIM;
    const signed char* Bg = wTq + (size_t)blockN0 * K_DIM;

    const int srow = wave * 16 + (lane >> 2);   // row within 64-row chunk
    const int scol = (lane & 3) * 16;           // byte offset within 64B row

    int4v acc[4][4];
    const int4v zero4 = {0, 0, 0, 0};
#pragma unroll
    for (int i = 0; i < 4; ++i)
#pragma unroll
        for (int j = 0; j < 4; ++j) acc[i][j] = zero4;

    // ---- prologue: stage tile 0 into buffer 0 ----
#pragma unroll
    for (int t = 0; t < 2; ++t) {
        const int r = t * 64 + srow;
        load_lds16(Ag + (size_t)r * K_DIM + scol, &A_lds[0][(t * 64 + wave * 16) * 64]);
        load_lds16(Bg + (size_t)r * K_DIM + scol, &B_lds[0][(t * 64 + wave * 16) * 64]);
    }

    int buf = 0;
    for (int kn = 64; kn <= K_DIM; kn += 64) {  // kn = offset of the NEXT tile
        __syncthreads();  // drains current buf's loads; frees alt buf from prior readers

        if (kn < K_DIM) {  // prefetch next tile into alternate buffer
            const int nb = buf ^ 1;
#pragma unroll
            for (int t = 0; t < 2; ++t) {
                const int r = t * 64 + srow;
                load_lds16(Ag + (size_t)r * K_DIM + kn + scol,
                           &A_lds[nb][(t * 64 + wave * 16) * 64]);
                load_lds16(Bg + (size_t)r * K_DIM + kn + scol,
                           &B_lds[nb][(t * 64 + wave * 16) * 64]);
            }
        }

        int4v a[4], b[4];
#pragma unroll
        for (int mt = 0; mt < 4; ++mt)
            a[mt] = *(const int4v*)&A_lds[buf][(waveM * 64 + mt * 16 + l15) * 64 + quad * 16];
#pragma unroll
        for (int nt = 0; nt < 4; ++nt)
            b[nt] = *(const int4v*)&B_lds[buf][(waveN * 64 + nt * 16 + l15) * 64 + quad * 16];

#pragma unroll
        for (int mt = 0; mt < 4; ++mt)
#pragma unroll
            for (int nt = 0; nt < 4; ++nt)
                acc[mt][nt] = __builtin_amdgcn_mfma_i32_16x16x64_i8(a[mt], b[nt],
                                                                    acc[mt][nt], 0, 0, 0);
        buf ^= 1;
    }

    // epilogue: + b_q, rescale, rint, clip, dequant
    const float s_in  = *in_scale_p;
    const float s_out = *out_scale_p;
    const float wscale = __uint_as_float(*wmax_bits) / QMAXF;
    const float bias_scale = s_in * wscale;
    const float ratio = bias_scale / s_out;

#pragma unroll
    for (int nt = 0; nt < 4; ++nt) {
        const int col = blockN0 + waveN * 64 + nt * 16 + l15;
        const int bq = (int)rintf(bias[col] / bias_scale);
#pragma unroll
        for (int mt = 0; mt < 4; ++mt) {
#pragma unroll
            for (int r = 0; r < 4; ++r) {
                const int row = blockM0 + waveM * 64 + mt * 16 + quad * 4 + r;
                const int av = acc[mt][nt][r] + bq;
                float f = rintf((float)av * ratio);
                f = fminf(fmaxf(f, -128.0f), 127.0f);
                out[(size_t)row * N_DIM + col] = f * s_out;
            }
        }
    }
}

extern "C" void kernel_launch(void* const* d_in, const int* in_sizes, int n_in,
                              void* d_out, int out_size, void* d_ws, size_t ws_size,
                              hipStream_t stream) {
    const float* x         = (const float*)d_in[0];
    const float* w         = (const float*)d_in[1];
    const float* bias      = (const float*)d_in[2];
    const float* in_scale  = (const float*)d_in[3];
    const float* out_scale = (const float*)d_in[4];
    float* out = (float*)d_out;

    unsigned char* ws = (unsigned char*)d_ws;
    unsigned int* wmax_bits = (unsigned int*)ws;
    signed char* xq  = (signed char*)(ws + 256);
    signed char* wTq = (signed char*)(ws + 256 + (size_t)M_DIM * K_DIM);

    hipMemsetAsync(d_ws, 0, 256, stream);

    wmax_kernel<<<320, 256, 0, stream>>>(w, wmax_bits, (K_DIM * N_DIM) / 4);

    quantx_kernel<<<(M_DIM * K_DIM / 4 + 255) / 256, 256, 0, stream>>>(
        x, xq, in_scale, M_DIM * K_DIM / 4);

    dim3 wgrid(N_DIM / 64, K_DIM / 64);  // (100, 25)
    quantw_kernel<<<wgrid, 256, 0, stream>>>(w, wTq, wmax_bits);

    dim3 ggrid(N_DIM / 128, M_DIM / 128);  // (50, 64)
    gemm_i8_kernel<<<ggrid, 256, 0, stream>>>(xq, wTq, bias, wmax_bits,
                                              in_scale, out_scale, out);
}

// Round 5
// 413.049 us; speedup vs baseline: 1.2812x; 1.0118x over previous
//
#include <hip/hip_runtime.h>

// out = dequant( int8_gemm( quant(x, in_scale), quant(w, absmax/127) ) + b_q )
// M = 8192, K = 1600, N = 6400.
// R5: XCD-aware block swizzle. R4 dbuf was neutral -> per-block latency already
// hidden by TLP. But FETCH=235MB vs 23MB of inputs (10x HBM over-fetch): B
// cycles through every XCD-L2, out-writes thrash L3. Swizzle: XCD j owns
// M-stripe [8j,8j+8), sweeps N outer/M inner -> working set ~4MB = L2.

#define M_DIM 8192
#define K_DIM 1600
#define N_DIM 6400
#define QMAXF 127.0f

typedef __attribute__((ext_vector_type(4))) int int4v;

// ---------------- ws layout ----------------
// [0, 4)            : uint bits of max|w|  (atomicMax target; memset to 0 each call)
// [256, 256+M*K)    : x_q  int8, row-major [M][K]
// [.. , ..  +N*K)   : wT_q int8, row-major [N][K]  (transposed weight)

__device__ __forceinline__ void load_lds16(const void* gptr, void* lptr) {
    __builtin_amdgcn_global_load_lds((__attribute__((address_space(1))) void*)gptr,
                                     (__attribute__((address_space(3))) void*)lptr,
                                     16, 0, 0);
}

// ---------------- absmax(weight): wave reduce -> LDS -> 1 atomic/block ----------------
__global__ void wmax_kernel(const float* __restrict__ w,
                            unsigned int* __restrict__ wmax_bits, int n4) {
    __shared__ float smax[4];
    const float4* w4 = (const float4*)w;
    int i = blockIdx.x * blockDim.x + threadIdx.x;
    int stride = gridDim.x * blockDim.x;
    float m = 0.0f;
    for (; i < n4; i += stride) {
        float4 v = w4[i];
        m = fmaxf(m, fmaxf(fmaxf(fabsf(v.x), fabsf(v.y)),
                           fmaxf(fabsf(v.z), fabsf(v.w))));
    }
#pragma unroll
    for (int off = 32; off > 0; off >>= 1)
        m = fmaxf(m, __shfl_down(m, off, 64));
    const int wave = threadIdx.x >> 6;
    if ((threadIdx.x & 63) == 0) smax[wave] = m;
    __syncthreads();
    if (threadIdx.x == 0) {
        float mm = fmaxf(fmaxf(smax[0], smax[1]), fmaxf(smax[2], smax[3]));
        atomicMax(wmax_bits, __float_as_uint(mm));  // mm >= 0: uint order == float order
    }
}

// ---------------- quantize x -> int8 [M][K] ----------------
__global__ void quantx_kernel(const float* __restrict__ x, signed char* __restrict__ xq,
                              const float* __restrict__ in_scale_p, int n4) {
    int i = blockIdx.x * blockDim.x + threadIdx.x;
    if (i >= n4) return;
    float s = *in_scale_p;
    float4 v = ((const float4*)x)[i];
    float a = fminf(fmaxf(rintf(v.x / s), -128.0f), 127.0f);
    float b = fminf(fmaxf(rintf(v.y / s), -128.0f), 127.0f);
    float c = fminf(fmaxf(rintf(v.z / s), -128.0f), 127.0f);
    float d = fminf(fmaxf(rintf(v.w / s), -128.0f), 127.0f);
    char4 packed = make_char4((signed char)a, (signed char)b,
                              (signed char)c, (signed char)d);
    ((char4*)xq)[i] = packed;
}

// ---------------- quantize + transpose w -> int8 [N][K], 64x64 tile ----------------
__global__ void quantw_kernel(const float* __restrict__ w, signed char* __restrict__ wT,
                              const unsigned int* __restrict__ wmax_bits) {
    __shared__ signed char tile[64 * 80];  // [n][k], stride 80 keeps 16B alignment
    const float wscale = __uint_as_float(*wmax_bits) / QMAXF;
    const int n0 = blockIdx.x * 64;
    const int k0 = blockIdx.y * 64;
    const int tid = threadIdx.x;
    const int nn = tid & 63;
    const int kb = tid >> 6;  // 0..3
#pragma unroll
    for (int p = 0; p < 16; ++p) {
        const int kk = p * 4 + kb;
        float v = w[(size_t)(k0 + kk) * N_DIM + n0 + nn];  // coalesced along n
        float q = fminf(fmaxf(rintf(v / wscale), -128.0f), 127.0f);
        tile[nn * 80 + kk] = (signed char)q;               // transposed in LDS
    }
    __syncthreads();
    const int n_loc = tid >> 2;
    const int kq = tid & 3;
    int4v val = *(const int4v*)&tile[n_loc * 80 + kq * 16];
    *(int4v*)&wT[(size_t)(n0 + n_loc) * K_DIM + k0 + kq * 16] = val;
}

// ------- int8 GEMM, 128x128 tile, BK=64, dbuf LDS, XCD swizzle, fused epilogue -------
__global__ __launch_bounds__(256, 2) void gemm_i8_kernel(
        const signed char* __restrict__ xq, const signed char* __restrict__ wTq,
        const float* __restrict__ bias, const unsigned int* __restrict__ wmax_bits,
        const float* __restrict__ in_scale_p, const float* __restrict__ out_scale_p,
        float* __restrict__ out) {
    __shared__ signed char A_lds[2][128 * 64];  // 2 x 8 KB  [m][k]
    __shared__ signed char B_lds[2][128 * 64];  // 2 x 8 KB  [n][k]

    const int tid   = threadIdx.x;
    const int wave  = tid >> 6;
    const int lane  = tid & 63;
    const int quad  = lane >> 4;
    const int l15   = lane & 15;
    const int waveM = wave >> 1;
    const int waveN = wave & 1;

    // XCD-aware swizzle: round-robin dispatch puts gid%8 on XCD gid&7.
    // XCD j owns m-blocks [8j, 8j+8); within an XCD: n outer, m inner.
    // Resident set per XCD ~ A-stripe 1.64MB + ~12 B-slabs 2.5MB ~= 4MB L2.
    const int gid   = blockIdx.x;           // 0..3199
    const int xcd   = gid & 7;
    const int idx   = gid >> 3;             // 0..399
    const int n_blk = idx >> 3;             // 0..49
    const int m_blk = (xcd << 3) | (idx & 7);  // 0..63

    const int blockN0 = n_blk * 128;
    const int blockM0 = m_blk * 128;

    const signed char* Ag = xq  + (size_t)blockM0 * K_DIM;
    const signed char* Bg = wTq + (size_t)blockN0 * K_DIM;

    const int srow = wave * 16 + (lane >> 2);   // row within 64-row chunk
    const int scol = (lane & 3) * 16;           // byte offset within 64B row

    int4v acc[4][4];
    const int4v zero4 = {0, 0, 0, 0};
#pragma unroll
    for (int i = 0; i < 4; ++i)
#pragma unroll
        for (int j = 0; j < 4; ++j) acc[i][j] = zero4;

    // ---- prologue: stage tile 0 into buffer 0 ----
#pragma unroll
    for (int t = 0; t < 2; ++t) {
        const int r = t * 64 + srow;
        load_lds16(Ag + (size_t)r * K_DIM + scol, &A_lds[0][(t * 64 + wave * 16) * 64]);
        load_lds16(Bg + (size_t)r * K_DIM + scol, &B_lds[0][(t * 64 + wave * 16) * 64]);
    }

    int buf = 0;
    for (int kn = 64; kn <= K_DIM; kn += 64) {  // kn = offset of the NEXT tile
        __syncthreads();

        if (kn < K_DIM) {  // prefetch next tile into alternate buffer
            const int nb = buf ^ 1;
#pragma unroll
            for (int t = 0; t < 2; ++t) {
                const int r = t * 64 + srow;
                load_lds16(Ag + (size_t)r * K_DIM + kn + scol,
                           &A_lds[nb][(t * 64 + wave * 16) * 64]);
                load_lds16(Bg + (size_t)r * K_DIM + kn + scol,
                           &B_lds[nb][(t * 64 + wave * 16) * 64]);
            }
        }

        int4v a[4], b[4];
#pragma unroll
        for (int mt = 0; mt < 4; ++mt)
            a[mt] = *(const int4v*)&A_lds[buf][(waveM * 64 + mt * 16 + l15) * 64 + quad * 16];
#pragma unroll
        for (int nt = 0; nt < 4; ++nt)
            b[nt] = *(const int4v*)&B_lds[buf][(waveN * 64 + nt * 16 + l15) * 64 + quad * 16];

#pragma unroll
        for (int mt = 0; mt < 4; ++mt)
#pragma unroll
            for (int nt = 0; nt < 4; ++nt)
                acc[mt][nt] = __builtin_amdgcn_mfma_i32_16x16x64_i8(a[mt], b[nt],
                                                                    acc[mt][nt], 0, 0, 0);
        buf ^= 1;
    }

    // epilogue: + b_q, rescale, rint, clip, dequant
    const float s_in  = *in_scale_p;
    const float s_out = *out_scale_p;
    const float wscale = __uint_as_float(*wmax_bits) / QMAXF;
    const float bias_scale = s_in * wscale;
    const float ratio = bias_scale / s_out;

#pragma unroll
    for (int nt = 0; nt < 4; ++nt) {
        const int col = blockN0 + waveN * 64 + nt * 16 + l15;
        const int bq = (int)rintf(bias[col] / bias_scale);
#pragma unroll
        for (int mt = 0; mt < 4; ++mt) {
#pragma unroll
            for (int r = 0; r < 4; ++r) {
                const int row = blockM0 + waveM * 64 + mt * 16 + quad * 4 + r;
                const int av = acc[mt][nt][r] + bq;
                float f = rintf((float)av * ratio);
                f = fminf(fmaxf(f, -128.0f), 127.0f);
                out[(size_t)row * N_DIM + col] = f * s_out;
            }
        }
    }
}

extern "C" void kernel_launch(void* const* d_in, const int* in_sizes, int n_in,
                              void* d_out, int out_size, void* d_ws, size_t ws_size,
                              hipStream_t stream) {
    const float* x         = (const float*)d_in[0];
    const float* w         = (const float*)d_in[1];
    const float* bias      = (const float*)d_in[2];
    const float* in_scale  = (const float*)d_in[3];
    const float* out_scale = (const float*)d_in[4];
    float* out = (float*)d_out;

    unsigned char* ws = (unsigned char*)d_ws;
    unsigned int* wmax_bits = (unsigned int*)ws;
    signed char* xq  = (signed char*)(ws + 256);
    signed char* wTq = (signed char*)(ws + 256 + (size_t)M_DIM * K_DIM);

    hipMemsetAsync(d_ws, 0, 256, stream);

    wmax_kernel<<<320, 256, 0, stream>>>(w, wmax_bits, (K_DIM * N_DIM) / 4);

    quantx_kernel<<<(M_DIM * K_DIM / 4 + 255) / 256, 256, 0, stream>>>(
        x, xq, in_scale, M_DIM * K_DIM / 4);

    dim3 wgrid(N_DIM / 64, K_DIM / 64);  // (100, 25)
    quantw_kernel<<<wgrid, 256, 0, stream>>>(w, wTq, wmax_bits);

    gemm_i8_kernel<<<3200, 256, 0, stream>>>(xq, wTq, bias, wmax_bits,
                                             in_scale, out_scale, out);
}